// Round 3
// baseline (984.555 us; speedup 1.0000x reference)
//
#include <hip/hip_runtime.h>
#include <stdint.h>

// FAVOR+ attention forward, MI355X. Round 3: fit workspace <=224 MiB
// (round 1/2 aborts = GPU memory fault from ws overrun; ws_size is likely 256 MiB).
// B=4 S=4096 H=8 KD=64 D=512 R=256 CHUNK=128 NC=32

namespace {
constexpr int kB = 4;
constexpr int kS = 4096;
constexpr int kH = 8;
constexpr int kD = 512;   // H*KD
constexpr int kR = 256;
constexpr int kNC = 32;   // S / 128
constexpr float kEPS = 1e-3f;
constexpr float kSCALE = 0.125f;  // 1/sqrt(64)
}

__device__ __forceinline__ float bflo(uint32_t w) {
  union { uint32_t u; float f; } c; c.u = w << 16; return c.f;
}
__device__ __forceinline__ float bfhi(uint32_t w) {
  union { uint32_t u; float f; } c; c.u = w & 0xffff0000u; return c.f;
}
__device__ __forceinline__ float bf2f(uint16_t u) {
  union { uint32_t i; float f; } c; c.i = ((uint32_t)u) << 16; return c.f;
}
__device__ __forceinline__ uint16_t f2bf(float x) {  // RNE
  union { float f; uint32_t i; } c; c.f = x;
  uint32_t r = c.i + 0x7fffu + ((c.i >> 16) & 1u);
  return (uint16_t)(r >> 16);
}

// ---------------- generic fp32 GEMM: O = A[M,K] @ W[K,N] (+bias) -------------
// tile 128x128, 256 threads, 8x8 per thread, K-step 8. LDS 8448 B.
template <bool BF16OUT>
__global__ __launch_bounds__(256) void gemm_f32(
    const float* __restrict__ A, const float* __restrict__ W,
    const float* __restrict__ bias, void* __restrict__ O,
    int M, int N, int K)
{
  __shared__ float As[8][132];  // As[k][m] (transposed)
  __shared__ float Bs[8][132];  // Bs[k][n]
  const int tid = threadIdx.x;
  const int tx = tid & 15, ty = tid >> 4;
  const int m0 = blockIdx.x * 128;
  const int n0 = blockIdx.y * 128;
  const int arow = tid >> 1, akq = (tid & 1) * 4;
  const int brow = tid >> 5, bcol = (tid & 31) * 4;

  float acc[8][8];
#pragma unroll
  for (int i = 0; i < 8; ++i)
#pragma unroll
    for (int j = 0; j < 8; ++j) acc[i][j] = 0.0f;

  for (int k0 = 0; k0 < K; k0 += 8) {
    float4 av = *(const float4*)(A + (size_t)(m0 + arow) * K + k0 + akq);
    float4 bv = *(const float4*)(W + (size_t)(k0 + brow) * N + n0 + bcol);
    As[akq + 0][arow] = av.x;
    As[akq + 1][arow] = av.y;
    As[akq + 2][arow] = av.z;
    As[akq + 3][arow] = av.w;
    *(float4*)&Bs[brow][bcol] = bv;
    __syncthreads();
#pragma unroll
    for (int kk = 0; kk < 8; ++kk) {
      float4 a0 = *(const float4*)&As[kk][ty * 8];
      float4 a1 = *(const float4*)&As[kk][ty * 8 + 4];
      float4 b0 = *(const float4*)&Bs[kk][tx * 4];
      float4 b1 = *(const float4*)&Bs[kk][64 + tx * 4];
      float aa[8] = {a0.x, a0.y, a0.z, a0.w, a1.x, a1.y, a1.z, a1.w};
      float bb[8] = {b0.x, b0.y, b0.z, b0.w, b1.x, b1.y, b1.z, b1.w};
#pragma unroll
      for (int i = 0; i < 8; ++i)
#pragma unroll
        for (int j = 0; j < 8; ++j) acc[i][j] += aa[i] * bb[j];
    }
    __syncthreads();
  }

  float badd[8];
#pragma unroll
  for (int j = 0; j < 4; ++j) {
    badd[j]     = bias ? bias[n0 + tx * 4 + j]      : 0.0f;
    badd[4 + j] = bias ? bias[n0 + 64 + tx * 4 + j] : 0.0f;
  }
#pragma unroll
  for (int i = 0; i < 8; ++i) {
    size_t m = (size_t)m0 + ty * 8 + i;
    if constexpr (!BF16OUT) {
      float* Of = (float*)O;
      float4 o0 = make_float4(acc[i][0] + badd[0], acc[i][1] + badd[1],
                              acc[i][2] + badd[2], acc[i][3] + badd[3]);
      float4 o1 = make_float4(acc[i][4] + badd[4], acc[i][5] + badd[5],
                              acc[i][6] + badd[6], acc[i][7] + badd[7]);
      *(float4*)(Of + m * N + n0 + tx * 4) = o0;
      *(float4*)(Of + m * N + n0 + 64 + tx * 4) = o1;
    } else {
      uint16_t* Ob = (uint16_t*)O;
      uint2 o0, o1;
      o0.x = (uint32_t)f2bf(acc[i][0] + badd[0]) | ((uint32_t)f2bf(acc[i][1] + badd[1]) << 16);
      o0.y = (uint32_t)f2bf(acc[i][2] + badd[2]) | ((uint32_t)f2bf(acc[i][3] + badd[3]) << 16);
      o1.x = (uint32_t)f2bf(acc[i][4] + badd[4]) | ((uint32_t)f2bf(acc[i][5] + badd[5]) << 16);
      o1.y = (uint32_t)f2bf(acc[i][6] + badd[6]) | ((uint32_t)f2bf(acc[i][7] + badd[7]) << 16);
      *(uint2*)(Ob + m * N + n0 + tx * 4) = o0;
      *(uint2*)(Ob + m * N + n0 + 64 + tx * 4) = o1;
    }
  }
}

// ---------------- features: p = (rows[M,64] @ rf^T)*SCALE; exp(p-max)+eps ----
// one block = 64 rows; full R=256 per block. grid.y: 0=q,1=k. LDS 50688 B.
__global__ __launch_bounds__(256) void feat_kernel(
    const float* __restrict__ qsrc, const float* __restrict__ ksrc,
    const float* __restrict__ rfm,
    uint16_t* __restrict__ qf, uint16_t* __restrict__ kf)
{
  __shared__ float in_m[64][68];        // 17408 B
  __shared__ uint16_t rf_t[64][260];    // rf_t[k][r] bf16, 33280 B
  const float* src = blockIdx.y ? ksrc : qsrc;
  uint16_t* dst = blockIdx.y ? kf : qf;
  const int tid = threadIdx.x;
  const size_t m0 = (size_t)blockIdx.x * 64;

#pragma unroll
  for (int i = 0; i < 4; ++i) {
    int idx = tid + 256 * i;
    int m = idx >> 4, k4 = (idx & 15) * 4;
    float4 a = *(const float4*)(src + (m0 + m) * 64 + k4);
    *(float4*)&in_m[m][k4] = a;
  }
#pragma unroll
  for (int k4 = 0; k4 < 16; ++k4) {  // thread tid = feature row r
    float4 vv = *(const float4*)(rfm + (size_t)tid * 64 + k4 * 4);
    rf_t[k4 * 4 + 0][tid] = f2bf(vv.x);
    rf_t[k4 * 4 + 1][tid] = f2bf(vv.y);
    rf_t[k4 * 4 + 2][tid] = f2bf(vv.z);
    rf_t[k4 * 4 + 3][tid] = f2bf(vv.w);
  }
  __syncthreads();

  const int tx = tid & 15, ty = tid >> 4;
  float acc[4][16];
#pragma unroll
  for (int i = 0; i < 4; ++i)
#pragma unroll
    for (int j = 0; j < 16; ++j) acc[i][j] = 0.0f;

  for (int k = 0; k < 64; ++k) {
    float aa[4];
#pragma unroll
    for (int i = 0; i < 4; ++i) aa[i] = in_m[ty * 4 + i][k];
#pragma unroll
    for (int nt = 0; nt < 4; ++nt) {
      uint2 bw = *(const uint2*)&rf_t[k][nt * 64 + tx * 4];
      float bb[4] = {bflo(bw.x), bfhi(bw.x), bflo(bw.y), bfhi(bw.y)};
#pragma unroll
      for (int i = 0; i < 4; ++i)
#pragma unroll
        for (int j = 0; j < 4; ++j)
          acc[i][nt * 4 + j] += aa[i] * bb[j];
    }
  }

#pragma unroll
  for (int i = 0; i < 4; ++i) {
    float mx = -1e30f;
#pragma unroll
    for (int c2 = 0; c2 < 16; ++c2) {
      acc[i][c2] *= kSCALE;
      mx = fmaxf(mx, acc[i][c2]);
    }
    mx = fmaxf(mx, __shfl_xor(mx, 1));
    mx = fmaxf(mx, __shfl_xor(mx, 2));
    mx = fmaxf(mx, __shfl_xor(mx, 4));
    mx = fmaxf(mx, __shfl_xor(mx, 8));
    size_t m = m0 + ty * 4 + i;
#pragma unroll
    for (int nt = 0; nt < 4; ++nt) {
      uint32_t w0 = (uint32_t)f2bf(__expf(acc[i][nt*4+0] - mx) + kEPS)
                  | ((uint32_t)f2bf(__expf(acc[i][nt*4+1] - mx) + kEPS) << 16);
      uint32_t w1 = (uint32_t)f2bf(__expf(acc[i][nt*4+2] - mx) + kEPS)
                  | ((uint32_t)f2bf(__expf(acc[i][nt*4+3] - mx) + kEPS) << 16);
      uint2 w; w.x = w0; w.y = w1;
      *(uint2*)(dst + m * 256 + nt * 64 + tx * 4) = w;
    }
  }
}

// ---------------- per-chunk sums: Skv_c = kf_c^T @ v_c ; Zc = sum_t kf -------
// v bf16 in, Skv bf16 out. LDS 32768 B.
__global__ __launch_bounds__(256) void chunk_sum(
    const uint16_t* __restrict__ kfeat, const uint16_t* __restrict__ vbuf,
    uint16_t* __restrict__ Skv, float* __restrict__ Zc)
{
  __shared__ float v_l[128][64];  // 32768 B
  const int c = blockIdx.x, bh = blockIdx.y;
  const int b = bh >> 3, h = bh & 7;
  const int tid = threadIdx.x;
#pragma unroll
  for (int i = 0; i < 4; ++i) {
    int idx = tid + 256 * i;          // 1024 x uint4 (8 bf16)
    int t = idx >> 3, g = idx & 7;
    uint4 w = *(const uint4*)(vbuf + ((size_t)b * kS + c * 128 + t) * kD + h * 64 + g * 8);
    float* vp = &v_l[t][g * 8];
    vp[0] = bflo(w.x); vp[1] = bfhi(w.x); vp[2] = bflo(w.y); vp[3] = bfhi(w.y);
    vp[4] = bflo(w.z); vp[5] = bfhi(w.z); vp[6] = bflo(w.w); vp[7] = bfhi(w.w);
  }
  __syncthreads();

  const int rg = tid >> 2, dq = tid & 3;  // r = rg*4+a, d = dq*16+j
  float acc[4][16];
#pragma unroll
  for (int a = 0; a < 4; ++a)
#pragma unroll
    for (int j = 0; j < 16; ++j) acc[a][j] = 0.0f;
  float zacc[4] = {0.f, 0.f, 0.f, 0.f};

  const uint16_t* kp = kfeat + (((size_t)b * kS + c * 128) * kH + h) * kR + rg * 4;
  for (int t = 0; t < 128; ++t) {
    uint2 kw = *(const uint2*)(kp + (size_t)t * (kH * kR));
    float kv[4] = {bflo(kw.x), bfhi(kw.x), bflo(kw.y), bfhi(kw.y)};
#pragma unroll
    for (int a = 0; a < 4; ++a) zacc[a] += kv[a];
#pragma unroll
    for (int j4 = 0; j4 < 4; ++j4) {
      float4 vv = *(const float4*)&v_l[t][dq * 16 + j4 * 4];
#pragma unroll
      for (int a = 0; a < 4; ++a) {
        acc[a][j4*4+0] += kv[a] * vv.x;
        acc[a][j4*4+1] += kv[a] * vv.y;
        acc[a][j4*4+2] += kv[a] * vv.z;
        acc[a][j4*4+3] += kv[a] * vv.w;
      }
    }
  }

  size_t base = (((size_t)bh * kNC + c) * kR + rg * 4) * 64 + dq * 16;
#pragma unroll
  for (int a = 0; a < 4; ++a)
#pragma unroll
    for (int j4 = 0; j4 < 4; ++j4) {
      uint2 o;
      o.x = (uint32_t)f2bf(acc[a][j4*4+0]) | ((uint32_t)f2bf(acc[a][j4*4+1]) << 16);
      o.y = (uint32_t)f2bf(acc[a][j4*4+2]) | ((uint32_t)f2bf(acc[a][j4*4+3]) << 16);
      *(uint2*)(Skv + base + (size_t)a * 64 + j4 * 4) = o;
    }
  if (dq == 0) {
#pragma unroll
    for (int a = 0; a < 4; ++a)
      Zc[((size_t)bh * kNC + c) * kR + rg * 4 + a] = zacc[a];
  }
}

// ---------------- exclusive prefix over chunks (in place, fp32 running) -----
__global__ __launch_bounds__(256) void prefix_kernel(
    uint16_t* __restrict__ Skv, float* __restrict__ Zc)
{
  const int nS = kB * kH * kR * 64;  // 524288
  int e = blockIdx.x * 256 + threadIdx.x;
  if (e < nS) {
    int bhm = e >> 14;        // / (R*KD = 16384)
    int rd = e & 16383;
    size_t base = (size_t)bhm * kNC * 16384 + rd;
    float run = 0.f;
    for (int c = 0; c < kNC; ++c) {
      size_t idx = base + (size_t)c * 16384;
      float val = bf2f(Skv[idx]);
      Skv[idx] = f2bf(run);
      run += val;
    }
  } else {
    int e2 = e - nS;
    if (e2 < kB * kH * kR) {
      int bhm = e2 >> 8;
      int r = e2 & 255;
      size_t base = (size_t)bhm * kNC * kR + r;
      float run = 0.f;
      for (int c = 0; c < kNC; ++c) {
        size_t idx = base + (size_t)c * kR;
        float val = Zc[idx];
        Zc[idx] = run;
        run += val;
      }
    }
  }
}

// ---------------- per-chunk output (64 t-rows per block) ---------------------
// out = (tril(qf@kf^T) @ v + qf@S_prev) / (rowsum(trilA) + qf.Z_prev + EPS)
// LDS: 33280 + 17408 + 4608 + 8704 + 256 + 1024 = 65280 B
__global__ __launch_bounds__(256) void favor_out(
    const uint16_t* __restrict__ qfeat, const uint16_t* __restrict__ kfeat,
    const uint16_t* __restrict__ vbuf, const uint16_t* __restrict__ Skv,
    const float* __restrict__ Zc, float* __restrict__ attn)
{
  __shared__ uint16_t qf_l[64][260];   // 33280 B
  __shared__ float    uni[64 * 68];    // 17408 B: S fp32 [64][68] | kf bf16 [32][268]
  __shared__ uint16_t A_l[64][36];     //  4608 B
  __shared__ float    v_t[32][68];     //  8704 B
  __shared__ float    den_b[64];       //   256 B
  __shared__ float    z_l[256];        //  1024 B

  uint16_t (*kf_l)[268] = (uint16_t (*)[268])uni;
  float (*S_t)[68] = (float (*)[68])uni;

  const int c = blockIdx.x;
  const int half = blockIdx.y;
  const int bh = blockIdx.z;
  const int b = bh >> 3, h = bh & 7;
  const int tid = threadIdx.x;
  const int t0 = half * 64;

  {  // stage qf rows [t0, t0+64)
    const uint16_t* qp = qfeat + (((size_t)b * kS + (size_t)c * 128 + t0) * kH + h) * kR;
#pragma unroll
    for (int i = 0; i < 16; ++i) {
      int idx = tid + 256 * i;
      int row = idx >> 6, c4 = idx & 63;
      uint2 w = *(const uint2*)(qp + (size_t)row * (kH * kR) + c4 * 4);
      *(uint2*)&qf_l[row][c4 * 4] = w;
    }
  }
  z_l[tid] = Zc[((size_t)bh * kNC + c) * kR + tid];
  if (tid < 64) den_b[tid] = 0.0f;

  const int tg = tid >> 2, dq = tid & 3;  // consumer: row tg, d cols dq*16..+15
  float num[16];
#pragma unroll
  for (int d = 0; d < 16; ++d) num[d] = 0.0f;
  float den = 0.0f;

  // phase 2: num += qf @ S_prev ; den += qf . Z_prev
  const uint16_t* Sg = Skv + ((size_t)bh * kNC + c) * (kR * 64);
  for (int rt = 0; rt < 4; ++rt) {
    __syncthreads();
#pragma unroll
    for (int i = 0; i < 2; ++i) {
      int idx = tid + 256 * i;          // 512 x uint4 (8 bf16)
      int rr = idx >> 3, g = idx & 7;
      uint4 w = *(const uint4*)(Sg + ((size_t)rt * 64 + rr) * 64 + g * 8);
      float* sp = &S_t[rr][g * 8];
      sp[0] = bflo(w.x); sp[1] = bfhi(w.x); sp[2] = bflo(w.y); sp[3] = bfhi(w.y);
      sp[4] = bflo(w.z); sp[5] = bfhi(w.z); sp[6] = bflo(w.w); sp[7] = bfhi(w.w);
    }
    __syncthreads();
    for (int rr4 = 0; rr4 < 16; ++rr4) {
      uint2 qw = *(const uint2*)&qf_l[tg][rt * 64 + rr4 * 4];
      float qv[4] = {bflo(qw.x), bfhi(qw.x), bflo(qw.y), bfhi(qw.y)};
#pragma unroll
      for (int jj = 0; jj < 4; ++jj) {
        int rr = rr4 * 4 + jj;
        float q = qv[jj];
        den += q * z_l[rt * 64 + rr];
#pragma unroll
        for (int j4 = 0; j4 < 4; ++j4) {
          float4 sv = *(const float4*)&S_t[rr][dq * 16 + j4 * 4];
          num[j4*4+0] += q * sv.x;
          num[j4*4+1] += q * sv.y;
          num[j4*4+2] += q * sv.z;
          num[j4*4+3] += q * sv.w;
        }
      }
    }
  }

  // phase 3: u-tiles of 32 rows
  const int p = tid >> 3, uq = tid & 7;  // A rows {2p,2p+1}, u cols uq*4..+3
  const int nut = 2 + half * 2;
  for (int ut = 0; ut < nut; ++ut) {
    const int u0 = ut * 32;
    __syncthreads();
    {  // stage kf rows [u0,u0+32) bf16 and v rows (bf16 -> fp32)
      const uint16_t* kp = kfeat + (((size_t)b * kS + (size_t)c * 128 + u0) * kH + h) * kR;
#pragma unroll
      for (int i = 0; i < 8; ++i) {
        int idx = tid + 256 * i;
        int row = idx >> 6, c4 = idx & 63;
        uint2 w = *(const uint2*)(kp + (size_t)row * (kH * kR) + c4 * 4);
        *(uint2*)&kf_l[row][c4 * 4] = w;
      }
      const uint16_t* vp = vbuf + ((size_t)b * kS + (size_t)c * 128 + u0) * kD + h * 64;
      {
        int row = tid >> 3, g = tid & 7;  // 256 x uint4 (8 bf16) = 32x64
        uint4 w = *(const uint4*)(vp + (size_t)row * kD + g * 8);
        float* dst = &v_t[row][g * 8];
        dst[0] = bflo(w.x); dst[1] = bfhi(w.x); dst[2] = bflo(w.y); dst[3] = bfhi(w.y);
        dst[4] = bflo(w.z); dst[5] = bfhi(w.z); dst[6] = bflo(w.w); dst[7] = bfhi(w.w);
      }
    }
    __syncthreads();
    {  // A = tril(qf @ kf^T), den partials in fp32
      float a_acc[2][4];
#pragma unroll
      for (int i = 0; i < 2; ++i)
#pragma unroll
        for (int u = 0; u < 4; ++u) a_acc[i][u] = 0.0f;
      for (int r4 = 0; r4 < 64; ++r4) {
        int r = r4 * 4;
        uint2 qw0 = *(const uint2*)&qf_l[2 * p][r];
        uint2 qw1 = *(const uint2*)&qf_l[2 * p + 1][r];
        float q0[4] = {bflo(qw0.x), bfhi(qw0.x), bflo(qw0.y), bfhi(qw0.y)};
        float q1[4] = {bflo(qw1.x), bfhi(qw1.x), bflo(qw1.y), bfhi(qw1.y)};
#pragma unroll
        for (int u = 0; u < 4; ++u) {
          uint2 kw = *(const uint2*)&kf_l[uq * 4 + u][r];
          float kv0 = bflo(kw.x), kv1 = bfhi(kw.x), kv2 = bflo(kw.y), kv3 = bfhi(kw.y);
          a_acc[0][u] += q0[0]*kv0 + q0[1]*kv1 + q0[2]*kv2 + q0[3]*kv3;
          a_acc[1][u] += q1[0]*kv0 + q1[1]*kv1 + q1[2]*kv2 + q1[3]*kv3;
        }
      }
      float s0 = 0.f, s1 = 0.f;
#pragma unroll
      for (int u = 0; u < 4; ++u) {
        int ug = u0 + uq * 4 + u;
        float a0 = (ug <= t0 + 2 * p)     ? a_acc[0][u] : 0.0f;
        float a1 = (ug <= t0 + 2 * p + 1) ? a_acc[1][u] : 0.0f;
        s0 += a0; s1 += a1;
        A_l[2 * p][uq * 4 + u]     = f2bf(a0);
        A_l[2 * p + 1][uq * 4 + u] = f2bf(a1);
      }
      s0 += __shfl_xor(s0, 1); s0 += __shfl_xor(s0, 2); s0 += __shfl_xor(s0, 4);
      s1 += __shfl_xor(s1, 1); s1 += __shfl_xor(s1, 2); s1 += __shfl_xor(s1, 4);
      if (uq == 0) {
        den_b[2 * p]     += s0;
        den_b[2 * p + 1] += s1;
      }
    }
    __syncthreads();
    // consume: num += A @ v
    for (int uu = 0; uu < 32; ++uu) {
      float a = bf2f(A_l[tg][uu]);
#pragma unroll
      for (int j4 = 0; j4 < 4; ++j4) {
        float4 vv = *(const float4*)&v_t[uu][dq * 16 + j4 * 4];
        num[j4*4+0] += a * vv.x;
        num[j4*4+1] += a * vv.y;
        num[j4*4+2] += a * vv.z;
        num[j4*4+3] += a * vv.w;
      }
    }
  }

  __syncthreads();
  den += den_b[tg];
  float inv = 1.0f / (den + kEPS);
  float* op = attn + ((size_t)b * kS + (size_t)c * 128 + t0 + tg) * kD + h * 64 + dq * 16;
#pragma unroll
  for (int j4 = 0; j4 < 4; ++j4) {
    float4 o = make_float4(num[j4*4+0] * inv, num[j4*4+1] * inv,
                           num[j4*4+2] * inv, num[j4*4+3] * inv);
    *(float4*)(op + j4 * 4) = o;
  }
}

// ---------------- launch -----------------------------------------------------
extern "C" void kernel_launch(void* const* d_in, const int* in_sizes, int n_in,
                              void* d_out, int out_size, void* d_ws, size_t ws_size,
                              hipStream_t stream)
{
  (void)in_sizes; (void)n_in; (void)out_size; (void)ws_size;
  const float* x  = (const float*)d_in[0];
  const float* Wq = (const float*)d_in[1];
  const float* Wk = (const float*)d_in[2];
  const float* Wv = (const float*)d_in[3];
  const float* Wo = (const float*)d_in[4];
  const float* bo = (const float*)d_in[5];
  const float* rf = (const float*)d_in[6];
  float* out = (float*)d_out;

  // ws layout (peak 224 MiB):
  //   [0,32MiB)    k f32        -> after feat: v bf16 [0,16MiB), Zc f32 [16,17MiB)
  //   [32,96MiB)   qf bf16
  //   [96,160MiB)  kf bf16
  //   [160,192MiB) Skv bf16
  //   [192,224MiB) attn f32
  // q f32 lives in d_out (overwritten by the final GEMM).
  char* ws = (char*)d_ws;
  float*    kbuf = (float*)ws;
  uint16_t* v16  = (uint16_t*)ws;
  float*    Zc   = (float*)(ws + 16777216);
  uint16_t* qf   = (uint16_t*)(ws + 33554432);
  uint16_t* kf   = (uint16_t*)(ws + 100663296);
  uint16_t* Skv  = (uint16_t*)(ws + 167772160);
  float*    attn = (float*)(ws + 201326592);
  float*    q    = out;  // d_out as scratch for q

  const int M = kB * kS;  // 16384
  gemm_f32<false><<<dim3(128, 4, 1), 256, 0, stream>>>(x, Wq, nullptr, q, M, kD, kD);
  gemm_f32<false><<<dim3(128, 4, 1), 256, 0, stream>>>(x, Wk, nullptr, kbuf, M, kD, kD);

  feat_kernel<<<dim3(2048, 2, 1), 256, 0, stream>>>(q, kbuf, rf, qf, kf);

  // kbuf dead; v (bf16) overwrites its first half.
  gemm_f32<true><<<dim3(128, 4, 1), 256, 0, stream>>>(x, Wv, nullptr, v16, M, kD, kD);

  chunk_sum<<<dim3(kNC, kB * kH, 1), 256, 0, stream>>>(kf, v16, Skv, Zc);
  prefix_kernel<<<dim3(2080, 1, 1), 256, 0, stream>>>(Skv, Zc);
  favor_out<<<dim3(kNC, 2, kB * kH), 256, 0, stream>>>(qf, kf, v16, Skv, Zc, attn);

  gemm_f32<false><<<dim3(128, 4, 1), 256, 0, stream>>>(attn, Wo, bo, out, M, kD, kD);
}

// Round 4
// 415.915 us; speedup vs baseline: 2.3672x; 2.3672x over previous
//
#include <hip/hip_runtime.h>
#include <stdint.h>

// FAVOR+ attention forward, MI355X. Round 4: MFMA bf16 everywhere.
// B=4 S=4096 H=8 KD=64 D=512 R=256 CHUNK=128 NC=32

namespace {
constexpr int kB = 4;
constexpr int kS = 4096;
constexpr int kH = 8;
constexpr int kD = 512;   // H*KD
constexpr int kR = 256;
constexpr int kNC = 32;   // S / 128
constexpr float kEPS = 1e-3f;
constexpr float kSCALE = 0.125f;  // 1/sqrt(64)
constexpr int kSP = 80;          // augmented state rows (64 d + 1 Z + 15 pad)
constexpr int kSST = kSP * 256;  // 20480 elements per (bh, c) state
}

typedef __attribute__((ext_vector_type(8))) short bf16x8;
typedef __attribute__((ext_vector_type(4))) float f32x4;

__device__ __forceinline__ f32x4 mfma16(bf16x8 a, bf16x8 b, f32x4 c) {
  return __builtin_amdgcn_mfma_f32_16x16x32_bf16(a, b, c, 0, 0, 0);
}

__device__ __forceinline__ float bflo(uint32_t w) {
  union { uint32_t u; float f; } c; c.u = w << 16; return c.f;
}
__device__ __forceinline__ float bfhi(uint32_t w) {
  union { uint32_t u; float f; } c; c.u = w & 0xffff0000u; return c.f;
}
__device__ __forceinline__ uint16_t f2bf(float x) {  // RNE
  union { float f; uint32_t i; } c; c.f = x;
  uint32_t r = c.i + 0x7fffu + ((c.i >> 16) & 1u);
  return (uint16_t)(r >> 16);
}

// ---------------- prep: cast x and rf to bf16 --------------------------------
__global__ __launch_bounds__(256) void cast_inputs(
    const float* __restrict__ x, const float* __restrict__ rfm,
    uint16_t* __restrict__ x16, uint16_t* __restrict__ rf16)
{
  int i4 = blockIdx.x * 256 + threadIdx.x;
  const int n1 = 2097152;  // x float4 count (16384*512/4)
  const int n2 = 4096;     // rf float4 count (256*64/4)
  const float* src; uint16_t* dst; int off;
  if (i4 < n1) { src = x; dst = x16; off = i4; }
  else if (i4 < n1 + n2) { src = rfm; dst = rf16; off = i4 - n1; }
  else return;
  float4 v = *(const float4*)(src + (size_t)off * 4);
  uint2 o;
  o.x = (uint32_t)f2bf(v.x) | ((uint32_t)f2bf(v.y) << 16);
  o.y = (uint32_t)f2bf(v.z) | ((uint32_t)f2bf(v.w) << 16);
  *(uint2*)(dst + (size_t)off * 4) = o;
}

// ---------------- prep: Wt16[n][k] = bf16(W[k][n]) ---------------------------
__global__ __launch_bounds__(256) void transpose_w(
    const float* __restrict__ W, uint16_t* __restrict__ Wt)
{
  __shared__ uint16_t t16[64][72];
  const int tid = threadIdx.x;
  const int k0 = blockIdx.x * 64, n0 = blockIdx.y * 64;
#pragma unroll
  for (int i = 0; i < 4; ++i) {
    int idx = tid + 256 * i;
    int kk = idx >> 4, nn4 = (idx & 15) * 4;
    float4 v = *(const float4*)(W + (size_t)(k0 + kk) * 512 + n0 + nn4);
    t16[kk][nn4 + 0] = f2bf(v.x);
    t16[kk][nn4 + 1] = f2bf(v.y);
    t16[kk][nn4 + 2] = f2bf(v.z);
    t16[kk][nn4 + 3] = f2bf(v.w);
  }
  __syncthreads();
#pragma unroll
  for (int i = 0; i < 4; ++i) {
    int idx = tid + 256 * i;
    int nn = idx >> 4, kk4 = (idx & 15) * 4;
    uint2 o;
    o.x = (uint32_t)t16[kk4 + 0][nn] | ((uint32_t)t16[kk4 + 1][nn] << 16);
    o.y = (uint32_t)t16[kk4 + 2][nn] | ((uint32_t)t16[kk4 + 3][nn] << 16);
    *(uint2*)(Wt + (size_t)(n0 + nn) * 512 + k0 + kk4) = o;
  }
}

// ---------------- bf16 MFMA GEMM: O = A[M,512] @ Bt^T (+bias) ---------------
// Bt is [n][k]. grid (M/128, 512/64), block 256 (4 waves x 32 rows). No LDS.
template <bool BF16OUT>
__global__ __launch_bounds__(256) void gemm_bf16(
    const uint16_t* __restrict__ A, const uint16_t* __restrict__ Bt,
    const float* __restrict__ bias, void* __restrict__ O)
{
  const int tid = threadIdx.x;
  const int w = tid >> 6, lane = tid & 63;
  const int lr = lane & 15, lg = lane >> 4;
  const int m_base = blockIdx.x * 128 + w * 32;
  const int n_base = blockIdx.y * 64;

  f32x4 acc[2][4];
#pragma unroll
  for (int mf = 0; mf < 2; ++mf)
#pragma unroll
    for (int nf = 0; nf < 4; ++nf) acc[mf][nf] = (f32x4){0.f, 0.f, 0.f, 0.f};

  const uint16_t* a0p = A + (size_t)(m_base + lr) * 512 + 8 * lg;
  const uint16_t* a1p = a0p + (size_t)16 * 512;
  const uint16_t* bp = Bt + (size_t)(n_base + lr) * 512 + 8 * lg;

#pragma unroll
  for (int ks = 0; ks < 16; ++ks) {
    bf16x8 a0 = *(const bf16x8*)(a0p + ks * 32);
    bf16x8 a1 = *(const bf16x8*)(a1p + ks * 32);
#pragma unroll
    for (int nf = 0; nf < 4; ++nf) {
      bf16x8 b = *(const bf16x8*)(bp + (size_t)nf * 16 * 512 + ks * 32);
      acc[0][nf] = mfma16(a0, b, acc[0][nf]);
      acc[1][nf] = mfma16(a1, b, acc[1][nf]);
    }
  }

  float badd[4];
#pragma unroll
  for (int nf = 0; nf < 4; ++nf)
    badd[nf] = bias ? bias[n_base + nf * 16 + lr] : 0.0f;

#pragma unroll
  for (int mf = 0; mf < 2; ++mf)
#pragma unroll
    for (int reg = 0; reg < 4; ++reg) {
      size_t m = (size_t)m_base + mf * 16 + 4 * lg + reg;
#pragma unroll
      for (int nf = 0; nf < 4; ++nf) {
        float v = acc[mf][nf][reg] + badd[nf];
        if constexpr (BF16OUT)
          ((uint16_t*)O)[m * 512 + n_base + nf * 16 + lr] = f2bf(v);
        else
          ((float*)O)[m * 512 + n_base + nf * 16 + lr] = v;
      }
    }
}

// ---------------- features via MFMA ------------------------------------------
// p = (q16 rows @ rf^T)*SCALE; out = exp(p - rowmax) + EPS -> bf16 [t][h][r]
// grid.x = (16384/64)*8 (t-group, h), grid.y: 0=q, 1=k. block 256 = 4 waves x 16 rows.
__global__ __launch_bounds__(256) void feat_mfma(
    const uint16_t* __restrict__ q16, const uint16_t* __restrict__ k16,
    const uint16_t* __restrict__ rf16,
    uint16_t* __restrict__ qf, uint16_t* __restrict__ kf)
{
  const uint16_t* src = blockIdx.y ? k16 : q16;
  uint16_t* dst = blockIdx.y ? kf : qf;
  const int tgrp = blockIdx.x >> 3, h = blockIdx.x & 7;
  const int tid = threadIdx.x;
  const int w = tid >> 6, lane = tid & 63;
  const int lr = lane & 15, lg = lane >> 4;
  const int t0 = tgrp * 64 + w * 16;

  f32x4 acc[16];
#pragma unroll
  for (int nf = 0; nf < 16; ++nf) acc[nf] = (f32x4){0.f, 0.f, 0.f, 0.f};

  const uint16_t* ap = src + (size_t)(t0 + lr) * 512 + h * 64 + 8 * lg;
#pragma unroll
  for (int ks = 0; ks < 2; ++ks) {
    bf16x8 a = *(const bf16x8*)(ap + ks * 32);
#pragma unroll
    for (int nf = 0; nf < 16; ++nf) {
      bf16x8 b = *(const bf16x8*)(rf16 + (size_t)(nf * 16 + lr) * 64 + ks * 32 + 8 * lg);
      acc[nf] = mfma16(a, b, acc[nf]);
    }
  }

  float mx[4] = {-1e30f, -1e30f, -1e30f, -1e30f};
#pragma unroll
  for (int nf = 0; nf < 16; ++nf)
#pragma unroll
    for (int reg = 0; reg < 4; ++reg) {
      acc[nf][reg] *= kSCALE;
      mx[reg] = fmaxf(mx[reg], acc[nf][reg]);
    }
#pragma unroll
  for (int reg = 0; reg < 4; ++reg) {
    mx[reg] = fmaxf(mx[reg], __shfl_xor(mx[reg], 1));
    mx[reg] = fmaxf(mx[reg], __shfl_xor(mx[reg], 2));
    mx[reg] = fmaxf(mx[reg], __shfl_xor(mx[reg], 4));
    mx[reg] = fmaxf(mx[reg], __shfl_xor(mx[reg], 8));
  }
#pragma unroll
  for (int reg = 0; reg < 4; ++reg) {
    size_t t = (size_t)t0 + 4 * lg + reg;
    uint16_t* op = dst + (t * 8 + h) * 256 + lr;
#pragma unroll
    for (int nf = 0; nf < 16; ++nf)
      op[nf * 16] = f2bf(__expf(acc[nf][reg] - mx[reg]) + kEPS);
  }
}

// ---------------- per-chunk sums -> Skv_t[bh][c][80][256] -------------------
// rows 0..63: (kf_c^T v_c)^T i.e. [d][r]; row 64: Z_c[r]; rows 65..79: 0.
__global__ __launch_bounds__(256) void chunk_sum(
    const uint16_t* __restrict__ kfeat, const uint16_t* __restrict__ vbuf,
    uint16_t* __restrict__ Skv)
{
  __shared__ float v_l[128][64];  // 32768 B
  const int c = blockIdx.x, bh = blockIdx.y;
  const int b = bh >> 3, h = bh & 7;
  const int tid = threadIdx.x;
#pragma unroll
  for (int i = 0; i < 4; ++i) {
    int idx = tid + 256 * i;
    int t = idx >> 3, g = idx & 7;
    uint4 w = *(const uint4*)(vbuf + ((size_t)b * kS + c * 128 + t) * kD + h * 64 + g * 8);
    float* vp = &v_l[t][g * 8];
    vp[0] = bflo(w.x); vp[1] = bfhi(w.x); vp[2] = bflo(w.y); vp[3] = bfhi(w.y);
    vp[4] = bflo(w.z); vp[5] = bfhi(w.z); vp[6] = bflo(w.w); vp[7] = bfhi(w.w);
  }
  __syncthreads();

  const int rg = tid >> 2, dq = tid & 3;  // r = rg*4+a, d = dq*16+j
  float acc[4][16];
#pragma unroll
  for (int a = 0; a < 4; ++a)
#pragma unroll
    for (int j = 0; j < 16; ++j) acc[a][j] = 0.0f;
  float zacc[4] = {0.f, 0.f, 0.f, 0.f};

  const uint16_t* kp = kfeat + (((size_t)b * kS + c * 128) * kH + h) * kR + rg * 4;
  for (int t = 0; t < 128; ++t) {
    uint2 kw = *(const uint2*)(kp + (size_t)t * (kH * kR));
    float kv[4] = {bflo(kw.x), bfhi(kw.x), bflo(kw.y), bfhi(kw.y)};
#pragma unroll
    for (int a = 0; a < 4; ++a) zacc[a] += kv[a];
#pragma unroll
    for (int j4 = 0; j4 < 4; ++j4) {
      float4 vv = *(const float4*)&v_l[t][dq * 16 + j4 * 4];
#pragma unroll
      for (int a = 0; a < 4; ++a) {
        acc[a][j4*4+0] += kv[a] * vv.x;
        acc[a][j4*4+1] += kv[a] * vv.y;
        acc[a][j4*4+2] += kv[a] * vv.z;
        acc[a][j4*4+3] += kv[a] * vv.w;
      }
    }
  }

  uint16_t* base = Skv + ((size_t)bh * kNC + c) * kSST;
#pragma unroll
  for (int j = 0; j < 16; ++j) {  // write [d][r], r contiguous x4
    uint2 o;
    o.x = (uint32_t)f2bf(acc[0][j]) | ((uint32_t)f2bf(acc[1][j]) << 16);
    o.y = (uint32_t)f2bf(acc[2][j]) | ((uint32_t)f2bf(acc[3][j]) << 16);
    *(uint2*)(base + (size_t)(dq * 16 + j) * 256 + rg * 4) = o;
  }
  if (dq == 0) {  // Z row
    uint2 o;
    o.x = (uint32_t)f2bf(zacc[0]) | ((uint32_t)f2bf(zacc[1]) << 16);
    o.y = (uint32_t)f2bf(zacc[2]) | ((uint32_t)f2bf(zacc[3]) << 16);
    *(uint2*)(base + (size_t)64 * 256 + rg * 4) = o;
  }
#pragma unroll
  for (int i = 0; i < 15; ++i)  // zero pad rows (determinism)
    base[(size_t)(65 + i) * 256 + tid] = 0;
}

// ---------------- exclusive prefix over chunks (in place) --------------------
__global__ __launch_bounds__(256) void prefix_kernel(uint16_t* __restrict__ Skv)
{
  int e = blockIdx.x * 256 + threadIdx.x;  // 32 bh * 20480
  int bh = e / kSST;
  int rd = e - bh * kSST;
  size_t base = (size_t)bh * kNC * kSST + rd;
  float run = 0.f;
  for (int c = 0; c < kNC; ++c) {
    size_t idx = base + (size_t)c * kSST;
    union { uint32_t i; float f; } cv; cv.i = ((uint32_t)Skv[idx]) << 16;
    Skv[idx] = f2bf(run);
    run += cv.f;
  }
}

// ---------------- favor_out via MFMA -----------------------------------------
// grid (nc, bh), block 256 = 4 waves; wave w owns t-strip [w*32,(w+1)*32).
// O[t][0:64] = tril(QF KF^T) Vaug + QF Saug ; col 64 = den.
__global__ __launch_bounds__(256) void favor_mfma(
    const uint16_t* __restrict__ qfeat, const uint16_t* __restrict__ kfeat,
    const uint16_t* __restrict__ vbuf, const uint16_t* __restrict__ Skv,
    uint16_t* __restrict__ attn16)
{
  __shared__ uint16_t Vaug[80][136];     // 21760 B, [d][u] transposed + ones row
  __shared__ uint16_t A_l[4][32][40];    // 10240 B, per-wave masked A tile

  const int c = blockIdx.x, bh = blockIdx.y;
  const int b = bh >> 3, h = bh & 7;
  const int tid = threadIdx.x;
  const int w = tid >> 6, lane = tid & 63;
  const int lr = lane & 15, lg = lane >> 4;
  const size_t srow = (size_t)b * kS + (size_t)c * 128;  // chunk base row

  // ---- stage Vaug (transposed), ones row, zero pad rows ----
#pragma unroll
  for (int i = 0; i < 4; ++i) {
    int idx = tid + 256 * i;
    int u = idx & 127, d = (idx >> 7) * 8;
    uint4 w8 = *(const uint4*)(vbuf + (srow + u) * kD + h * 64 + d);
    Vaug[d + 0][u] = (uint16_t)(w8.x & 0xffff);
    Vaug[d + 1][u] = (uint16_t)(w8.x >> 16);
    Vaug[d + 2][u] = (uint16_t)(w8.y & 0xffff);
    Vaug[d + 3][u] = (uint16_t)(w8.y >> 16);
    Vaug[d + 4][u] = (uint16_t)(w8.z & 0xffff);
    Vaug[d + 5][u] = (uint16_t)(w8.z >> 16);
    Vaug[d + 6][u] = (uint16_t)(w8.w & 0xffff);
    Vaug[d + 7][u] = (uint16_t)(w8.w >> 16);
  }
  if (tid < 128) Vaug[64][tid] = 0x3F80;  // bf16(1.0)
  if (tid < 136) {
#pragma unroll
    for (int rr = 65; rr < 80; ++rr) Vaug[rr][tid] = 0;
  }

  // ---- QF strip into registers (16 frags) ----
  bf16x8 qa[2][8];
  const uint16_t* qp = qfeat + ((srow + w * 32 + lr) * kH + h) * kR + 8 * lg;
#pragma unroll
  for (int mf = 0; mf < 2; ++mf)
#pragma unroll
    for (int ks = 0; ks < 8; ++ks)
      qa[mf][ks] = *(const bf16x8*)(qp + (size_t)mf * 16 * (kH * kR) + ks * 32);

  f32x4 o[2][5];
#pragma unroll
  for (int mf = 0; mf < 2; ++mf)
#pragma unroll
    for (int nf = 0; nf < 5; ++nf) o[mf][nf] = (f32x4){0.f, 0.f, 0.f, 0.f};

  // ---- QF @ Saug (global B-frags; col 64 accumulates den via Z row) ----
  const uint16_t* Sg = Skv + ((size_t)bh * kNC + c) * kSST + 8 * lg;
#pragma unroll
  for (int ks = 0; ks < 8; ++ks) {
#pragma unroll
    for (int nf = 0; nf < 5; ++nf) {
      bf16x8 sb = *(const bf16x8*)(Sg + (size_t)(nf * 16 + lr) * 256 + ks * 32);
      o[0][nf] = mfma16(qa[0][ks], sb, o[0][nf]);
      o[1][nf] = mfma16(qa[1][ks], sb, o[1][nf]);
    }
  }

  __syncthreads();

  // ---- causal u-tiles: QK^T -> mask -> A_l -> A @ Vaug ----
  const uint16_t* kp = kfeat + (srow + lr) * (kH * kR) + h * kR + 8 * lg;
  for (int ut = 0; ut <= w; ++ut) {
    f32x4 aacc[2][2];
#pragma unroll
    for (int mf = 0; mf < 2; ++mf)
#pragma unroll
      for (int nf = 0; nf < 2; ++nf) aacc[mf][nf] = (f32x4){0.f, 0.f, 0.f, 0.f};
#pragma unroll
    for (int ks = 0; ks < 8; ++ks) {
      bf16x8 kb0 = *(const bf16x8*)(kp + (size_t)(ut * 32) * (kH * kR) + ks * 32);
      bf16x8 kb1 = *(const bf16x8*)(kp + (size_t)(ut * 32 + 16) * (kH * kR) + ks * 32);
      aacc[0][0] = mfma16(qa[0][ks], kb0, aacc[0][0]);
      aacc[0][1] = mfma16(qa[0][ks], kb1, aacc[0][1]);
      aacc[1][0] = mfma16(qa[1][ks], kb0, aacc[1][0]);
      aacc[1][1] = mfma16(qa[1][ks], kb1, aacc[1][1]);
    }
    // mask (diagonal tile only) + write bf16 A tile to per-wave LDS
#pragma unroll
    for (int mf = 0; mf < 2; ++mf)
#pragma unroll
      for (int nf = 0; nf < 2; ++nf)
#pragma unroll
        for (int reg = 0; reg < 4; ++reg) {
          int trow = mf * 16 + 4 * lg + reg;
          int ucol = nf * 16 + lr;
          float v = aacc[mf][nf][reg];
          if (ut == w && ucol > trow) v = 0.0f;
          A_l[w][trow][ucol] = f2bf(v);
        }
    // A-operand frags from LDS, B from Vaug
    bf16x8 af0 = *(const bf16x8*)&A_l[w][lr][8 * lg];
    bf16x8 af1 = *(const bf16x8*)&A_l[w][16 + lr][8 * lg];
#pragma unroll
    for (int nf = 0; nf < 5; ++nf) {
      bf16x8 vb = *(const bf16x8*)&Vaug[nf * 16 + lr][ut * 32 + 8 * lg];
      o[0][nf] = mfma16(af0, vb, o[0][nf]);
      o[1][nf] = mfma16(af1, vb, o[1][nf]);
    }
  }

  // ---- epilogue: divide by den (col 64), store bf16 attn ----
#pragma unroll
  for (int mf = 0; mf < 2; ++mf) {
    float inv[4];
#pragma unroll
    for (int reg = 0; reg < 4; ++reg) {
      float den = __shfl(o[mf][4][reg], lane & 48);
      inv[reg] = 1.0f / (den + kEPS);
    }
    const size_t trow = srow + w * 32 + mf * 16 + 4 * lg;
#pragma unroll
    for (int reg = 0; reg < 4; ++reg) {
      uint16_t* op = attn16 + (trow + reg) * kD + h * 64 + lr;
#pragma unroll
      for (int nf = 0; nf < 4; ++nf)
        op[nf * 16] = f2bf(o[mf][nf][reg] * inv[reg]);
    }
  }
}

// ---------------- launch -----------------------------------------------------
extern "C" void kernel_launch(void* const* d_in, const int* in_sizes, int n_in,
                              void* d_out, int out_size, void* d_ws, size_t ws_size,
                              hipStream_t stream)
{
  (void)in_sizes; (void)n_in; (void)out_size; (void)ws_size;
  const float* x  = (const float*)d_in[0];
  const float* Wq = (const float*)d_in[1];
  const float* Wk = (const float*)d_in[2];
  const float* Wv = (const float*)d_in[3];
  const float* Wo = (const float*)d_in[4];
  const float* bo = (const float*)d_in[5];
  const float* rf = (const float*)d_in[6];
  float* out = (float*)d_out;

  // ws layout (~218.1 MiB): x16 16M | k16/attn16 16M | v16 16M | qf 64M |
  // kf 64M | Skv_t 40M | Wqt/Wkt/Wvt/Wot 2M | rf16 32K.  q16 lives in d_out.
  char* ws = (char*)d_ws;
  uint16_t* x16   = (uint16_t*)ws;
  uint16_t* k16   = (uint16_t*)(ws + (16u << 20));
  uint16_t* v16   = (uint16_t*)(ws + (32u << 20));
  uint16_t* qf    = (uint16_t*)(ws + (48u << 20));
  uint16_t* kf    = (uint16_t*)(ws + (112u << 20));
  uint16_t* Skv   = (uint16_t*)(ws + (176u << 20));
  uint16_t* Wqt   = (uint16_t*)(ws + (216u << 20));
  uint16_t* Wkt   = Wqt + 262144;
  uint16_t* Wvt   = Wkt + 262144;
  uint16_t* Wot   = Wvt + 262144;
  uint16_t* rf16  = Wot + 262144;
  uint16_t* q16   = (uint16_t*)d_out;   // dead before the final GEMM writes out
  uint16_t* attn16 = k16;               // k16 dead after feat_mfma

  cast_inputs<<<dim3(8208, 1, 1), 256, 0, stream>>>(x, rf, x16, rf16);
  transpose_w<<<dim3(8, 8, 1), 256, 0, stream>>>(Wq, Wqt);
  transpose_w<<<dim3(8, 8, 1), 256, 0, stream>>>(Wk, Wkt);
  transpose_w<<<dim3(8, 8, 1), 256, 0, stream>>>(Wv, Wvt);
  transpose_w<<<dim3(8, 8, 1), 256, 0, stream>>>(Wo, Wot);

  gemm_bf16<true><<<dim3(128, 8, 1), 256, 0, stream>>>(x16, Wqt, nullptr, q16);
  gemm_bf16<true><<<dim3(128, 8, 1), 256, 0, stream>>>(x16, Wkt, nullptr, k16);
  gemm_bf16<true><<<dim3(128, 8, 1), 256, 0, stream>>>(x16, Wvt, nullptr, v16);

  feat_mfma<<<dim3(2048, 2, 1), 256, 0, stream>>>(q16, k16, rf16, qf, kf);

  chunk_sum<<<dim3(kNC, kB * kH, 1), 256, 0, stream>>>(kf, v16, Skv);
  prefix_kernel<<<dim3(2560, 1, 1), 256, 0, stream>>>(Skv);
  favor_mfma<<<dim3(kNC, kB * kH, 1), 256, 0, stream>>>(qf, kf, v16, Skv, attn16);

  gemm_bf16<false><<<dim3(128, 8, 1), 256, 0, stream>>>(attn16, Wot, bo, out);
}

// Round 5
// 397.180 us; speedup vs baseline: 2.4789x; 1.0472x over previous
//
#include <hip/hip_runtime.h>
#include <stdint.h>

// FAVOR+ attention forward, MI355X. Round 5: coalesced MFMA epilogues + MFMA chunk_sum.
// B=4 S=4096 H=8 KD=64 D=512 R=256 CHUNK=128 NC=32

namespace {
constexpr int kB = 4;
constexpr int kS = 4096;
constexpr int kH = 8;
constexpr int kD = 512;   // H*KD
constexpr int kR = 256;
constexpr int kNC = 32;   // S / 128
constexpr float kEPS = 1e-3f;
constexpr float kSCALE = 0.125f;  // 1/sqrt(64)
constexpr int kSP = 80;          // augmented state rows (64 d + 1 Z + 15 pad)
constexpr int kSST = kSP * 256;  // 20480 elements per (bh, c) state
}

typedef __attribute__((ext_vector_type(8))) short bf16x8;
typedef __attribute__((ext_vector_type(4))) float f32x4;

__device__ __forceinline__ f32x4 mfma16(bf16x8 a, bf16x8 b, f32x4 c) {
  return __builtin_amdgcn_mfma_f32_16x16x32_bf16(a, b, c, 0, 0, 0);
}

__device__ __forceinline__ float bflo(uint32_t w) {
  union { uint32_t u; float f; } c; c.u = w << 16; return c.f;
}
__device__ __forceinline__ float bfhi(uint32_t w) {
  union { uint32_t u; float f; } c; c.u = w & 0xffff0000u; return c.f;
}
__device__ __forceinline__ uint16_t f2bf(float x) {  // RNE
  union { float f; uint32_t i; } c; c.f = x;
  uint32_t r = c.i + 0x7fffu + ((c.i >> 16) & 1u);
  return (uint16_t)(r >> 16);
}

// ---------------- prep: cast x and rf to bf16 --------------------------------
__global__ __launch_bounds__(256) void cast_inputs(
    const float* __restrict__ x, const float* __restrict__ rfm,
    uint16_t* __restrict__ x16, uint16_t* __restrict__ rf16)
{
  int i4 = blockIdx.x * 256 + threadIdx.x;
  const int n1 = 2097152;  // x float4 count (16384*512/4)
  const int n2 = 4096;     // rf float4 count (256*64/4)
  const float* src; uint16_t* dst; int off;
  if (i4 < n1) { src = x; dst = x16; off = i4; }
  else if (i4 < n1 + n2) { src = rfm; dst = rf16; off = i4 - n1; }
  else return;
  float4 v = *(const float4*)(src + (size_t)off * 4);
  uint2 o;
  o.x = (uint32_t)f2bf(v.x) | ((uint32_t)f2bf(v.y) << 16);
  o.y = (uint32_t)f2bf(v.z) | ((uint32_t)f2bf(v.w) << 16);
  *(uint2*)(dst + (size_t)off * 4) = o;
}

// ---------------- prep: Wt16[z][n][k] = bf16(W_z[k][n]), z in 0..3 ----------
__global__ __launch_bounds__(256) void transpose_w(
    const float* __restrict__ Wq, const float* __restrict__ Wk,
    const float* __restrict__ Wv, const float* __restrict__ Wo,
    uint16_t* __restrict__ WtBase)
{
  __shared__ uint16_t t16[64][72];
  const int z = blockIdx.z;
  const float* W = (z == 0) ? Wq : (z == 1) ? Wk : (z == 2) ? Wv : Wo;
  uint16_t* Wt = WtBase + (size_t)z * 262144;
  const int tid = threadIdx.x;
  const int k0 = blockIdx.x * 64, n0 = blockIdx.y * 64;
#pragma unroll
  for (int i = 0; i < 4; ++i) {
    int idx = tid + 256 * i;
    int kk = idx >> 4, nn4 = (idx & 15) * 4;
    float4 v = *(const float4*)(W + (size_t)(k0 + kk) * 512 + n0 + nn4);
    t16[kk][nn4 + 0] = f2bf(v.x);
    t16[kk][nn4 + 1] = f2bf(v.y);
    t16[kk][nn4 + 2] = f2bf(v.z);
    t16[kk][nn4 + 3] = f2bf(v.w);
  }
  __syncthreads();
#pragma unroll
  for (int i = 0; i < 4; ++i) {
    int idx = tid + 256 * i;
    int nn = idx >> 4, kk4 = (idx & 15) * 4;
    uint2 o;
    o.x = (uint32_t)t16[kk4 + 0][nn] | ((uint32_t)t16[kk4 + 1][nn] << 16);
    o.y = (uint32_t)t16[kk4 + 2][nn] | ((uint32_t)t16[kk4 + 3][nn] << 16);
    *(uint2*)(Wt + (size_t)(n0 + nn) * 512 + k0 + kk4) = o;
  }
}

// ---------------- bf16 MFMA GEMM: O = A[M,512] @ Bt^T (+bias) ---------------
// Bt is [n][k]. grid (M/128, 512/64), block 256 (4 waves x 32 rows).
// Epilogue routes through per-wave LDS tile for coalesced 16B stores.
template <bool BF16OUT>
__global__ __launch_bounds__(256) void gemm_bf16(
    const uint16_t* __restrict__ A, const uint16_t* __restrict__ Bt,
    const float* __restrict__ bias, void* __restrict__ O)
{
  const int tid = threadIdx.x;
  const int w = tid >> 6, lane = tid & 63;
  const int lr = lane & 15, lg = lane >> 4;
  const int m_base = blockIdx.x * 128 + w * 32;
  const int n_base = blockIdx.y * 64;

  f32x4 acc[2][4];
#pragma unroll
  for (int mf = 0; mf < 2; ++mf)
#pragma unroll
    for (int nf = 0; nf < 4; ++nf) acc[mf][nf] = (f32x4){0.f, 0.f, 0.f, 0.f};

  const uint16_t* a0p = A + (size_t)(m_base + lr) * 512 + 8 * lg;
  const uint16_t* a1p = a0p + (size_t)16 * 512;
  const uint16_t* bp = Bt + (size_t)(n_base + lr) * 512 + 8 * lg;

#pragma unroll
  for (int ks = 0; ks < 16; ++ks) {
    bf16x8 a0 = *(const bf16x8*)(a0p + ks * 32);
    bf16x8 a1 = *(const bf16x8*)(a1p + ks * 32);
#pragma unroll
    for (int nf = 0; nf < 4; ++nf) {
      bf16x8 b = *(const bf16x8*)(bp + (size_t)nf * 16 * 512 + ks * 32);
      acc[0][nf] = mfma16(a0, b, acc[0][nf]);
      acc[1][nf] = mfma16(a1, b, acc[1][nf]);
    }
  }

  float badd[4];
#pragma unroll
  for (int nf = 0; nf < 4; ++nf)
    badd[nf] = bias ? bias[n_base + nf * 16 + lr] : 0.0f;

  if constexpr (BF16OUT) {
    __shared__ uint16_t tr[4][32][72];  // 18432 B
#pragma unroll
    for (int mf = 0; mf < 2; ++mf)
#pragma unroll
      for (int nf = 0; nf < 4; ++nf)
#pragma unroll
        for (int reg = 0; reg < 4; ++reg)
          tr[w][mf * 16 + 4 * lg + reg][nf * 16 + lr] = f2bf(acc[mf][nf][reg] + badd[nf]);
    __syncthreads();
#pragma unroll
    for (int it = 0; it < 4; ++it) {
      int idx = it * 64 + lane;
      int row = idx >> 3, c8 = (idx & 7) * 8;
      uint4 val = *(const uint4*)&tr[w][row][c8];
      *(uint4*)((uint16_t*)O + (size_t)(m_base + row) * 512 + n_base + c8) = val;
    }
  } else {
    __shared__ float trf[4][32][68];  // 34816 B
#pragma unroll
    for (int mf = 0; mf < 2; ++mf)
#pragma unroll
      for (int nf = 0; nf < 4; ++nf)
#pragma unroll
        for (int reg = 0; reg < 4; ++reg)
          trf[w][mf * 16 + 4 * lg + reg][nf * 16 + lr] = acc[mf][nf][reg] + badd[nf];
    __syncthreads();
#pragma unroll
    for (int it = 0; it < 8; ++it) {
      int idx = it * 64 + lane;
      int row = idx >> 4, c4 = (idx & 15) * 4;
      float4 val = *(const float4*)&trf[w][row][c4];
      *(float4*)((float*)O + (size_t)(m_base + row) * 512 + n_base + c4) = val;
    }
  }
}

// ---------------- features via MFMA ------------------------------------------
// p = (src rows @ rf^T)*SCALE; out = exp(p - rowmax) + EPS -> bf16 [t][h][r]
// grid.x = (16384/64)*8, grid.y: 0=q, 1=k. block 256 = 4 waves x 16 rows.
__global__ __launch_bounds__(256) void feat_mfma(
    const uint16_t* __restrict__ q16, const uint16_t* __restrict__ k16,
    const uint16_t* __restrict__ rf16,
    uint16_t* __restrict__ qf, uint16_t* __restrict__ kf)
{
  __shared__ uint16_t tr[4][16][264];  // 33792 B
  const uint16_t* src = blockIdx.y ? k16 : q16;
  uint16_t* dst = blockIdx.y ? kf : qf;
  const int tgrp = blockIdx.x >> 3, h = blockIdx.x & 7;
  const int tid = threadIdx.x;
  const int w = tid >> 6, lane = tid & 63;
  const int lr = lane & 15, lg = lane >> 4;
  const int t0 = tgrp * 64 + w * 16;

  f32x4 acc[16];
#pragma unroll
  for (int nf = 0; nf < 16; ++nf) acc[nf] = (f32x4){0.f, 0.f, 0.f, 0.f};

  const uint16_t* ap = src + (size_t)(t0 + lr) * 512 + h * 64 + 8 * lg;
#pragma unroll
  for (int ks = 0; ks < 2; ++ks) {
    bf16x8 a = *(const bf16x8*)(ap + ks * 32);
#pragma unroll
    for (int nf = 0; nf < 16; ++nf) {
      bf16x8 b = *(const bf16x8*)(rf16 + (size_t)(nf * 16 + lr) * 64 + ks * 32 + 8 * lg);
      acc[nf] = mfma16(a, b, acc[nf]);
    }
  }

  float mx[4] = {-1e30f, -1e30f, -1e30f, -1e30f};
#pragma unroll
  for (int nf = 0; nf < 16; ++nf)
#pragma unroll
    for (int reg = 0; reg < 4; ++reg) {
      acc[nf][reg] *= kSCALE;
      mx[reg] = fmaxf(mx[reg], acc[nf][reg]);
    }
#pragma unroll
  for (int reg = 0; reg < 4; ++reg) {
    mx[reg] = fmaxf(mx[reg], __shfl_xor(mx[reg], 1));
    mx[reg] = fmaxf(mx[reg], __shfl_xor(mx[reg], 2));
    mx[reg] = fmaxf(mx[reg], __shfl_xor(mx[reg], 4));
    mx[reg] = fmaxf(mx[reg], __shfl_xor(mx[reg], 8));
  }
  // fragments -> per-wave LDS tile (transpose), then coalesced 16B row stores
#pragma unroll
  for (int nf = 0; nf < 16; ++nf)
#pragma unroll
    for (int reg = 0; reg < 4; ++reg)
      tr[w][4 * lg + reg][nf * 16 + lr] = f2bf(__expf(acc[nf][reg] - mx[reg]) + kEPS);
  __syncthreads();
#pragma unroll
  for (int it = 0; it < 8; ++it) {
    int idx = it * 64 + lane;
    int row = idx >> 5, c8 = (idx & 31) * 8;
    uint4 val = *(const uint4*)&tr[w][row][c8];
    *(uint4*)(dst + ((size_t)(t0 + row) * 8 + h) * 256 + c8) = val;
  }
}

// ---------------- chunk_sum via MFMA -----------------------------------------
// Skv_t[bh][c][80][256]: rows 0..63 = (kf_c^T v_c)^T = V^T KF; row 64 = Z; 65..79 = 0.
// block (c,bh) = 256 thr, 4 waves; wave w owns r-cols [w*64,(w+1)*64).
// LDS: Vaug 80x136 (21760) + union(kfT 256x72 = 36864, outT 80x264 = 42240) = 64000 B.
__global__ __launch_bounds__(256) void chunk_mfma(
    const uint16_t* __restrict__ kfeat, const uint16_t* __restrict__ vbuf,
    uint16_t* __restrict__ Skv)
{
  __shared__ uint16_t Vaug[80][136];
  __shared__ uint16_t uni2[21120];  // 42240 B
  uint16_t (*kfT)[72] = (uint16_t (*)[72])uni2;
  uint16_t (*outT)[264] = (uint16_t (*)[264])uni2;

  const int c = blockIdx.x, bh = blockIdx.y;
  const int b = bh >> 3, h = bh & 7;
  const int tid = threadIdx.x;
  const int w = tid >> 6, lane = tid & 63;
  const int lr = lane & 15, lg = lane >> 4;
  const size_t srow = (size_t)b * kS + (size_t)c * 128;

  // ---- stage Vaug = [d][t] transposed V + ones row 64 + zero rows 65..79 ----
#pragma unroll
  for (int i = 0; i < 4; ++i) {
    int idx = tid + 256 * i;
    int u = idx & 127, d = (idx >> 7) * 8;
    uint4 w8 = *(const uint4*)(vbuf + (srow + u) * kD + h * 64 + d);
    Vaug[d + 0][u] = (uint16_t)(w8.x & 0xffff);
    Vaug[d + 1][u] = (uint16_t)(w8.x >> 16);
    Vaug[d + 2][u] = (uint16_t)(w8.y & 0xffff);
    Vaug[d + 3][u] = (uint16_t)(w8.y >> 16);
    Vaug[d + 4][u] = (uint16_t)(w8.z & 0xffff);
    Vaug[d + 5][u] = (uint16_t)(w8.z >> 16);
    Vaug[d + 6][u] = (uint16_t)(w8.w & 0xffff);
    Vaug[d + 7][u] = (uint16_t)(w8.w >> 16);
  }
  if (tid < 128) Vaug[64][tid] = 0x3F80;  // bf16(1.0)
  if (tid < 136) {
#pragma unroll
    for (int rr = 65; rr < 80; ++rr) Vaug[rr][tid] = 0;
  }

  f32x4 acc[5][4];
#pragma unroll
  for (int mf = 0; mf < 5; ++mf)
#pragma unroll
    for (int nf = 0; nf < 4; ++nf) acc[mf][nf] = (f32x4){0.f, 0.f, 0.f, 0.f};

  const uint16_t* kp0 = kfeat + (srow * kH + h) * kR;
#pragma unroll
  for (int th = 0; th < 2; ++th) {
    if (th) __syncthreads();  // waves done reading kfT half 0
    // stage kfT[r][t_local] for t_local in [0,64)
    const uint16_t* kp = kp0 + (size_t)th * 64 * (kH * kR);
#pragma unroll
    for (int i = 0; i < 16; ++i) {
      int idx = tid + 256 * i;           // 4096 uint2-chunks: t=idx>>6, 4r each
      int t = idx >> 6, c4 = idx & 63;
      uint2 wv = *(const uint2*)(kp + (size_t)t * (kH * kR) + c4 * 4);
      int r = c4 * 4;
      kfT[r + 0][t] = (uint16_t)(wv.x & 0xffff);
      kfT[r + 1][t] = (uint16_t)(wv.x >> 16);
      kfT[r + 2][t] = (uint16_t)(wv.y & 0xffff);
      kfT[r + 3][t] = (uint16_t)(wv.y >> 16);
    }
    __syncthreads();
#pragma unroll
    for (int ks = 0; ks < 2; ++ks) {
      bf16x8 af[5];
#pragma unroll
      for (int mf = 0; mf < 5; ++mf)
        af[mf] = *(const bf16x8*)&Vaug[mf * 16 + lr][th * 64 + ks * 32 + 8 * lg];
#pragma unroll
      for (int nf = 0; nf < 4; ++nf) {
        bf16x8 kb = *(const bf16x8*)&kfT[w * 64 + nf * 16 + lr][ks * 32 + 8 * lg];
#pragma unroll
        for (int mf = 0; mf < 5; ++mf)
          acc[mf][nf] = mfma16(af[mf], kb, acc[mf][nf]);
      }
    }
  }

  __syncthreads();  // kfT dead -> reuse as outT
#pragma unroll
  for (int mf = 0; mf < 5; ++mf)
#pragma unroll
    for (int nf = 0; nf < 4; ++nf)
#pragma unroll
      for (int reg = 0; reg < 4; ++reg)
        outT[mf * 16 + 4 * lg + reg][w * 64 + nf * 16 + lr] = f2bf(acc[mf][nf][reg]);
  __syncthreads();

  uint16_t* So = Skv + ((size_t)bh * kNC + c) * kSST;
#pragma unroll
  for (int it = 0; it < 10; ++it) {
    int idx = tid + 256 * it;            // 2560 uint4-chunks: 80 rows x 32
    int row = idx >> 5, c8 = (idx & 31) * 8;
    uint4 val = *(const uint4*)&outT[row][c8];
    *(uint4*)(So + (size_t)row * 256 + c8) = val;
  }
}

// ---------------- exclusive prefix over chunks (in place) --------------------
__global__ __launch_bounds__(256) void prefix_kernel(uint16_t* __restrict__ Skv)
{
  int e = blockIdx.x * 256 + threadIdx.x;  // 32 bh * 20480
  int bh = e / kSST;
  int rd = e - bh * kSST;
  size_t base = (size_t)bh * kNC * kSST + rd;
  float run = 0.f;
  for (int c = 0; c < kNC; ++c) {
    size_t idx = base + (size_t)c * kSST;
    union { uint32_t i; float f; } cv; cv.i = ((uint32_t)Skv[idx]) << 16;
    Skv[idx] = f2bf(run);
    run += cv.f;
  }
}

// ---------------- favor_out via MFMA -----------------------------------------
// grid (nc, bh), block 256 = 4 waves; wave w owns t-strip [w*32,(w+1)*32).
// O[t][0:64] = tril(QF KF^T) Vaug + QF Saug ; col 64 = den.
__global__ __launch_bounds__(256) void favor_mfma(
    const uint16_t* __restrict__ qfeat, const uint16_t* __restrict__ kfeat,
    const uint16_t* __restrict__ vbuf, const uint16_t* __restrict__ Skv,
    uint16_t* __restrict__ attn16)
{
  __shared__ uint16_t Vaug[80][136];     // 21760 B, [d][u] transposed + ones row
  __shared__ uint16_t A_l[4][32][40];    // 10240 B, per-wave masked A tile

  const int c = blockIdx.x, bh = blockIdx.y;
  const int b = bh >> 3, h = bh & 7;
  const int tid = threadIdx.x;
  const int w = tid >> 6, lane = tid & 63;
  const int lr = lane & 15, lg = lane >> 4;
  const size_t srow = (size_t)b * kS + (size_t)c * 128;  // chunk base row

  // ---- stage Vaug (transposed), ones row, zero pad rows ----
#pragma unroll
  for (int i = 0; i < 4; ++i) {
    int idx = tid + 256 * i;
    int u = idx & 127, d = (idx >> 7) * 8;
    uint4 w8 = *(const uint4*)(vbuf + (srow + u) * kD + h * 64 + d);
    Vaug[d + 0][u] = (uint16_t)(w8.x & 0xffff);
    Vaug[d + 1][u] = (uint16_t)(w8.x >> 16);
    Vaug[d + 2][u] = (uint16_t)(w8.y & 0xffff);
    Vaug[d + 3][u] = (uint16_t)(w8.y >> 16);
    Vaug[d + 4][u] = (uint16_t)(w8.z & 0xffff);
    Vaug[d + 5][u] = (uint16_t)(w8.z >> 16);
    Vaug[d + 6][u] = (uint16_t)(w8.w & 0xffff);
    Vaug[d + 7][u] = (uint16_t)(w8.w >> 16);
  }
  if (tid < 128) Vaug[64][tid] = 0x3F80;  // bf16(1.0)
  if (tid < 136) {
#pragma unroll
    for (int rr = 65; rr < 80; ++rr) Vaug[rr][tid] = 0;
  }

  // ---- QF strip into registers (16 frags) ----
  bf16x8 qa[2][8];
  const uint16_t* qp = qfeat + ((srow + w * 32 + lr) * kH + h) * kR + 8 * lg;
#pragma unroll
  for (int mf = 0; mf < 2; ++mf)
#pragma unroll
    for (int ks = 0; ks < 8; ++ks)
      qa[mf][ks] = *(const bf16x8*)(qp + (size_t)mf * 16 * (kH * kR) + ks * 32);

  f32x4 o[2][5];
#pragma unroll
  for (int mf = 0; mf < 2; ++mf)
#pragma unroll
    for (int nf = 0; nf < 5; ++nf) o[mf][nf] = (f32x4){0.f, 0.f, 0.f, 0.f};

  // ---- QF @ Saug (global B-frags; col 64 accumulates den via Z row) ----
  const uint16_t* Sg = Skv + ((size_t)bh * kNC + c) * kSST + 8 * lg;
#pragma unroll
  for (int ks = 0; ks < 8; ++ks) {
#pragma unroll
    for (int nf = 0; nf < 5; ++nf) {
      bf16x8 sb = *(const bf16x8*)(Sg + (size_t)(nf * 16 + lr) * 256 + ks * 32);
      o[0][nf] = mfma16(qa[0][ks], sb, o[0][nf]);
      o[1][nf] = mfma16(qa[1][ks], sb, o[1][nf]);
    }
  }

  __syncthreads();

  // ---- causal u-tiles: QK^T -> mask -> A_l -> A @ Vaug ----
  const uint16_t* kp = kfeat + (srow + lr) * (kH * kR) + h * kR + 8 * lg;
  for (int ut = 0; ut <= w; ++ut) {
    f32x4 aacc[2][2];
#pragma unroll
    for (int mf = 0; mf < 2; ++mf)
#pragma unroll
      for (int nf = 0; nf < 2; ++nf) aacc[mf][nf] = (f32x4){0.f, 0.f, 0.f, 0.f};
#pragma unroll
    for (int ks = 0; ks < 8; ++ks) {
      bf16x8 kb0 = *(const bf16x8*)(kp + (size_t)(ut * 32) * (kH * kR) + ks * 32);
      bf16x8 kb1 = *(const bf16x8*)(kp + (size_t)(ut * 32 + 16) * (kH * kR) + ks * 32);
      aacc[0][0] = mfma16(qa[0][ks], kb0, aacc[0][0]);
      aacc[0][1] = mfma16(qa[0][ks], kb1, aacc[0][1]);
      aacc[1][0] = mfma16(qa[1][ks], kb0, aacc[1][0]);
      aacc[1][1] = mfma16(qa[1][ks], kb1, aacc[1][1]);
    }
    // mask (diagonal tile only) + write bf16 A tile to per-wave LDS
#pragma unroll
    for (int mf = 0; mf < 2; ++mf)
#pragma unroll
      for (int nf = 0; nf < 2; ++nf)
#pragma unroll
        for (int reg = 0; reg < 4; ++reg) {
          int trow = mf * 16 + 4 * lg + reg;
          int ucol = nf * 16 + lr;
          float v = aacc[mf][nf][reg];
          if (ut == w && ucol > trow) v = 0.0f;
          A_l[w][trow][ucol] = f2bf(v);
        }
    // A-operand frags from LDS, B from Vaug
    bf16x8 af0 = *(const bf16x8*)&A_l[w][lr][8 * lg];
    bf16x8 af1 = *(const bf16x8*)&A_l[w][16 + lr][8 * lg];
#pragma unroll
    for (int nf = 0; nf < 5; ++nf) {
      bf16x8 vb = *(const bf16x8*)&Vaug[nf * 16 + lr][ut * 32 + 8 * lg];
      o[0][nf] = mfma16(af0, vb, o[0][nf]);
      o[1][nf] = mfma16(af1, vb, o[1][nf]);
    }
  }

  // ---- epilogue: divide by den (col 64), store bf16 attn ----
#pragma unroll
  for (int mf = 0; mf < 2; ++mf) {
    float inv[4];
#pragma unroll
    for (int reg = 0; reg < 4; ++reg) {
      float den = __shfl(o[mf][4][reg], lane & 48);
      inv[reg] = 1.0f / (den + kEPS);
    }
    const size_t trow = srow + w * 32 + mf * 16 + 4 * lg;
#pragma unroll
    for (int reg = 0; reg < 4; ++reg) {
      uint16_t* op = attn16 + (trow + reg) * kD + h * 64 + lr;
#pragma unroll
      for (int nf = 0; nf < 4; ++nf)
        op[nf * 16] = f2bf(o[mf][nf][reg] * inv[reg]);
    }
  }
}

// ---------------- launch -----------------------------------------------------
extern "C" void kernel_launch(void* const* d_in, const int* in_sizes, int n_in,
                              void* d_out, int out_size, void* d_ws, size_t ws_size,
                              hipStream_t stream)
{
  (void)in_sizes; (void)n_in; (void)out_size; (void)ws_size;
  const float* x  = (const float*)d_in[0];
  const float* Wq = (const float*)d_in[1];
  const float* Wk = (const float*)d_in[2];
  const float* Wv = (const float*)d_in[3];
  const float* Wo = (const float*)d_in[4];
  const float* bo = (const float*)d_in[5];
  const float* rf = (const float*)d_in[6];
  float* out = (float*)d_out;

  // ws layout (~218.1 MiB): x16 16M | k16/attn16 16M | v16 16M | qf 64M |
  // kf 64M | Skv_t 40M | Wt[4] 2M | rf16 32K.  q16 lives in d_out.
  char* ws = (char*)d_ws;
  uint16_t* x16   = (uint16_t*)ws;
  uint16_t* k16   = (uint16_t*)(ws + (16u << 20));
  uint16_t* v16   = (uint16_t*)(ws + (32u << 20));
  uint16_t* qf    = (uint16_t*)(ws + (48u << 20));
  uint16_t* kf    = (uint16_t*)(ws + (112u << 20));
  uint16_t* Skv   = (uint16_t*)(ws + (176u << 20));
  uint16_t* Wt    = (uint16_t*)(ws + (216u << 20));  // 4 x 262144
  uint16_t* rf16  = Wt + 4 * 262144;
  uint16_t* q16   = (uint16_t*)d_out;   // dead before the final GEMM writes out
  uint16_t* attn16 = k16;               // k16 dead after feat_mfma

  cast_inputs<<<dim3(8208, 1, 1), 256, 0, stream>>>(x, rf, x16, rf16);
  transpose_w<<<dim3(8, 8, 4), 256, 0, stream>>>(Wq, Wk, Wv, Wo, Wt);

  gemm_bf16<true><<<dim3(128, 8, 1), 256, 0, stream>>>(x16, Wt + 0 * 262144, nullptr, q16);
  gemm_bf16<true><<<dim3(128, 8, 1), 256, 0, stream>>>(x16, Wt + 1 * 262144, nullptr, k16);
  gemm_bf16<true><<<dim3(128, 8, 1), 256, 0, stream>>>(x16, Wt + 2 * 262144, nullptr, v16);

  feat_mfma<<<dim3(2048, 2, 1), 256, 0, stream>>>(q16, k16, rf16, qf, kf);

  chunk_mfma<<<dim3(kNC, kB * kH, 1), 256, 0, stream>>>(kf, v16, Skv);
  prefix_kernel<<<dim3(2560, 1, 1), 256, 0, stream>>>(Skv);
  favor_mfma<<<dim3(kNC, kB * kH, 1), 256, 0, stream>>>(qf, kf, v16, Skv, attn16);

  gemm_bf16<false><<<dim3(128, 8, 1), 256, 0, stream>>>(attn16, Wt + 3 * 262144, bo, out);
}